// Round 1
// baseline (233.765 us; speedup 1.0000x reference)
//
#include <hip/hip_runtime.h>
#include <hip/hip_bf16.h>
#include <stdint.h>

#define B_   8
#define S_   4096
#define SP1_ 4097
#define D_   256
#define R_   512
#define C_   2048

typedef __attribute__((ext_vector_type(8))) short bf16x8;
typedef __attribute__((ext_vector_type(4))) float f32x4;
typedef unsigned short u16;

__device__ __forceinline__ u16 f2bf(float f) {
  __hip_bfloat16 h = __float2bfloat16(f);
  return *(u16*)&h;
}
__device__ __forceinline__ float bf2f(u16 u) {
  __hip_bfloat16 h = *(__hip_bfloat16*)&u;
  return __bfloat162float(h);
}

// ---------------- cast pos tokens (x[:,1:,:]) to bf16, layout (B,S,D) ----------------
__global__ void k_cast_pos(const float* __restrict__ x, u16* __restrict__ posb) {
  int i = blockIdx.x * 256 + threadIdx.x;     // B*S*D/4 = 2,097,152 threads
  int g = i << 2;
  int b = g >> 20;                            // / (S_*D_) = 1048576
  int rem = g & 1048575;
  const float4 v = *(const float4*)(x + (size_t)b * SP1_ * D_ + D_ + rem);
  ushort4 u;
  u.x = f2bf(v.x); u.y = f2bf(v.y); u.z = f2bf(v.z); u.w = f2bf(v.w);
  *(ushort4*)(posb + g) = u;
}

// ---------------- w0[b,r] = sum_d cls[b,d] * cls_w[d,r] ----------------
__global__ void k_w0(const float* __restrict__ x, const float* __restrict__ clsw,
                     float* __restrict__ w0) {
  int i = blockIdx.x * 256 + threadIdx.x;     // 0..4095
  int b = i >> 9, r = i & 511;
  const float* cls = x + (size_t)b * SP1_ * D_;
  float a = 0.f;
  for (int d = 0; d < D_; d++) a += cls[d] * clsw[d * R_ + r];
  w0[i] = a;
}

// ---------------- proj[b,d,r] = softmax_r(cls[b,d]*w0[b,r] + cls_b[r]), bf16 ----------------
__global__ void k_softmax(const float* __restrict__ x, const float* __restrict__ w0,
                          const float* __restrict__ clsb, u16* __restrict__ proj) {
  int bd = blockIdx.x;                        // B*D = 2048 blocks
  int b = bd >> 8, d = bd & 255;
  float c = x[(size_t)b * SP1_ * D_ + d];
  int t = threadIdx.x;
  float l0 = c * w0[b * R_ + t] + clsb[t];
  float l1 = c * w0[b * R_ + t + 256] + clsb[t + 256];
  __shared__ float red[256];
  red[t] = fmaxf(l0, l1);
  __syncthreads();
  for (int st = 128; st; st >>= 1) { if (t < st) red[t] = fmaxf(red[t], red[t + st]); __syncthreads(); }
  float m = red[0];
  __syncthreads();
  float e0 = expf(l0 - m), e1 = expf(l1 - m);
  red[t] = e0 + e1;
  __syncthreads();
  for (int st = 128; st; st >>= 1) { if (t < st) red[t] += red[t + st]; __syncthreads(); }
  float inv = 1.0f / red[0];
  size_t base = ((size_t)b * D_ + d) * R_;
  proj[base + t]       = f2bf(e0 * inv);
  proj[base + t + 256] = f2bf(e1 * inv);
}

// ---------------- ET[c,r] = bf16(E[r,c])  (512x2048 -> 2048x512) ----------------
__global__ void k_transpose_E(const float* __restrict__ E, u16* __restrict__ ET) {
  __shared__ float tile[32][33];
  int c0 = blockIdx.x * 32, r0 = blockIdx.y * 32;
  int tx = threadIdx.x, ty = threadIdx.y;     // 32 x 8
  #pragma unroll
  for (int i = 0; i < 4; i++) {
    int r = r0 + ty + i * 8;
    tile[ty + i * 8][tx] = E[(size_t)r * C_ + c0 + tx];
  }
  __syncthreads();
  #pragma unroll
  for (int i = 0; i < 4; i++) {
    int c = c0 + ty + i * 8;
    ET[(size_t)c * R_ + r0 + tx] = f2bf(tile[tx][ty + i * 8]);
  }
}

// ---------------- emb GEMM: embT[b,c,d] = bf16( sum_r proj[b,d,r]*ET[c,r] ), esq[b,c] += emb^2 ----------------
__global__ __launch_bounds__(256) void k_gemm_emb(const u16* __restrict__ proj,
                                                  const u16* __restrict__ ET,
                                                  u16* __restrict__ embT,
                                                  float* __restrict__ esq) {
  int ct = blockIdx.x, mt = blockIdx.y, b = blockIdx.z;
  int n0 = ct * 128, m0 = mt * 128;
  const u16* A  = proj + (size_t)b * D_ * R_;   // D x R (row-major, k=r contiguous)
  const u16* Bt = ET;                           // C x R
  __shared__ u16 tA[4096], tB[4096];            // 128x32 each
  int tid = threadIdx.x;
  int wv = tid >> 6, lane = tid & 63, ln = lane & 15, qd = lane >> 4;
  f32x4 acc[2][8];
  #pragma unroll
  for (int mf = 0; mf < 2; mf++)
    #pragma unroll
    for (int nf = 0; nf < 8; nf++) acc[mf][nf] = (f32x4){0.f, 0.f, 0.f, 0.f};

  for (int kk = 0; kk < R_; kk += 32) {
    __syncthreads();
    #pragma unroll
    for (int i = 0; i < 2; i++) {
      int q = tid + i * 256, row = q >> 2, kc = q & 3;
      *(uint4*)&tA[row * 32 + kc * 8] = *(const uint4*)&A [(size_t)(m0 + row) * R_ + kk + kc * 8];
      *(uint4*)&tB[row * 32 + kc * 8] = *(const uint4*)&Bt[(size_t)(n0 + row) * R_ + kk + kc * 8];
    }
    __syncthreads();
    bf16x8 af[2], bfr[8];
    #pragma unroll
    for (int mf = 0; mf < 2; mf++) af[mf] = *(bf16x8*)&tA[(wv * 32 + mf * 16 + ln) * 32 + qd * 8];
    #pragma unroll
    for (int nf = 0; nf < 8; nf++) bfr[nf] = *(bf16x8*)&tB[(nf * 16 + ln) * 32 + qd * 8];
    #pragma unroll
    for (int mf = 0; mf < 2; mf++)
      #pragma unroll
      for (int nf = 0; nf < 8; nf++)
        acc[mf][nf] = __builtin_amdgcn_mfma_f32_16x16x32_bf16(af[mf], bfr[nf], acc[mf][nf], 0, 0, 0);
  }
  // epilogue: C[m=d][n=c]; write embT[c,d] (4 consecutive d per lane) + accumulate esq
  #pragma unroll
  for (int nf = 0; nf < 8; nf++) {
    int c = n0 + nf * 16 + ln;
    float ss = 0.f;
    #pragma unroll
    for (int mf = 0; mf < 2; mf++) {
      int dbase = m0 + wv * 32 + mf * 16 + qd * 4;
      f32x4 v = acc[mf][nf];
      ushort4 u;
      u.x = f2bf(v[0]); u.y = f2bf(v[1]); u.z = f2bf(v[2]); u.w = f2bf(v[3]);
      *(ushort4*)&embT[((size_t)b * C_ + c) * D_ + dbase] = u;
      ss += v[0]*v[0] + v[1]*v[1] + v[2]*v[2] + v[3]*v[3];
    }
    atomicAdd(&esq[b * C_ + c], ss);
  }
}

// ---------------- dist GEMM + per-tile argmin partials ----------------
__global__ __launch_bounds__(256) void k_gemm_dist(const u16* __restrict__ posb,
                                                   const u16* __restrict__ embT,
                                                   const float* __restrict__ esq,
                                                   float* __restrict__ pval,
                                                   int* __restrict__ pidx) {
  int ct = blockIdx.x, st = blockIdx.y, b = blockIdx.z;
  int n0 = ct * 128, m0 = st * 128;
  const u16* A  = posb + (size_t)b * S_ * D_;   // S x D
  const u16* Bt = embT + (size_t)b * C_ * D_;   // C x D
  __shared__ u16 tA[4096], tB[4096];
  __shared__ float sh_esq[128];
  int tid = threadIdx.x;
  if (tid < 128) sh_esq[tid] = esq[b * C_ + n0 + tid];
  int wv = tid >> 6, lane = tid & 63, ln = lane & 15, qd = lane >> 4;
  f32x4 acc[2][8];
  #pragma unroll
  for (int mf = 0; mf < 2; mf++)
    #pragma unroll
    for (int nf = 0; nf < 8; nf++) acc[mf][nf] = (f32x4){0.f, 0.f, 0.f, 0.f};

  for (int kk = 0; kk < D_; kk += 32) {
    __syncthreads();
    #pragma unroll
    for (int i = 0; i < 2; i++) {
      int q = tid + i * 256, row = q >> 2, kc = q & 3;
      *(uint4*)&tA[row * 32 + kc * 8] = *(const uint4*)&A [(size_t)(m0 + row) * D_ + kk + kc * 8];
      *(uint4*)&tB[row * 32 + kc * 8] = *(const uint4*)&Bt[(size_t)(n0 + row) * D_ + kk + kc * 8];
    }
    __syncthreads();
    bf16x8 af[2], bfr[8];
    #pragma unroll
    for (int mf = 0; mf < 2; mf++) af[mf] = *(bf16x8*)&tA[(wv * 32 + mf * 16 + ln) * 32 + qd * 8];
    #pragma unroll
    for (int nf = 0; nf < 8; nf++) bfr[nf] = *(bf16x8*)&tB[(nf * 16 + ln) * 32 + qd * 8];
    #pragma unroll
    for (int mf = 0; mf < 2; mf++)
      #pragma unroll
      for (int nf = 0; nf < 8; nf++)
        acc[mf][nf] = __builtin_amdgcn_mfma_f32_16x16x32_bf16(af[mf], bfr[nf], acc[mf][nf], 0, 0, 0);
  }
  // per-row argmin of score = esq[c] - 2*dot over this tile's 128 cols
  #pragma unroll
  for (int mf = 0; mf < 2; mf++) {
    #pragma unroll
    for (int reg = 0; reg < 4; reg++) {
      float bv = 3.4e38f; int bc = 0;
      #pragma unroll
      for (int nf = 0; nf < 8; nf++) {
        int c = nf * 16 + ln;
        float sc = sh_esq[c] - 2.0f * acc[mf][nf][reg];
        if (sc < bv || (sc == bv && c < bc)) { bv = sc; bc = c; }
      }
      #pragma unroll
      for (int off = 1; off < 16; off <<= 1) {
        float ov = __shfl_xor(bv, off);
        int   oc = __shfl_xor(bc, off);
        if (ov < bv || (ov == bv && oc < bc)) { bv = ov; bc = oc; }
      }
      if (ln == 0) {
        int s = m0 + wv * 32 + mf * 16 + qd * 4 + reg;
        size_t o = ((size_t)b * S_ + s) * 16 + ct;
        pval[o] = bv;
        pidx[o] = n0 + bc;
      }
    }
  }
}

// ---------------- reduce 16 tile-partials -> final index ----------------
__global__ void k_reduce_idx(const float* __restrict__ pval, const int* __restrict__ pidx,
                             int* __restrict__ idx) {
  int i = blockIdx.x * 256 + threadIdx.x;     // < B*S
  const float* pv = pval + (size_t)i * 16;
  const int*   pi = pidx + (size_t)i * 16;
  float bv = pv[0]; int bi = pi[0];
  #pragma unroll
  for (int j = 1; j < 16; j++) {
    float v = pv[j]; int ix = pi[j];
    if (v < bv || (v == bv && ix < bi)) { bv = v; bi = ix; }
  }
  idx[i] = bi;
}

// ---------------- gather quantized, write output, accumulate SSE; copy cls row ----------------
__global__ void k_gather(const float* __restrict__ x, const u16* __restrict__ embT,
                         const int* __restrict__ idx, float* __restrict__ out,
                         float* __restrict__ acc) {
  int ch = blockIdx.x, b = blockIdx.y, t = threadIdx.x;   // t = d
  size_t xb = (size_t)b * SP1_ * D_;
  if (ch == 0) out[xb + t] = x[xb + t];                   // cls token passthrough
  const u16* eb = embT + (size_t)b * C_ * D_;
  float lsum = 0.f;
  for (int j = 0; j < 128; j++) {
    int s = ch * 128 + j;
    int ix = idx[b * S_ + s];
    float q = bf2f(eb[(size_t)ix * D_ + t]);
    size_t o = xb + (size_t)(s + 1) * D_ + t;
    float p = x[o];
    out[o] = q;
    float df = q - p;
    lsum += df * df;
  }
  __shared__ float red[256];
  red[t] = lsum;
  __syncthreads();
  for (int st = 128; st; st >>= 1) { if (t < st) red[t] += red[t + st]; __syncthreads(); }
  if (t == 0) atomicAdd(&acc[0], red[0]);
}

// ---------------- histogram + perplexity ----------------
__global__ void k_hist(const int* __restrict__ idx, int* __restrict__ hist) {
  int i = blockIdx.x * 256 + threadIdx.x;     // < B*S
  int b = i >> 12;
  atomicAdd(&hist[b * C_ + idx[i]], 1);
}

__global__ void k_perp(const int* __restrict__ hist, float* __restrict__ acc) {
  int b = blockIdx.x, t = threadIdx.x;
  float ps = 0.f;
  for (int c = t; c < C_; c += 256) {
    float p = (float)hist[b * C_ + c] * (1.0f / (float)S_);
    ps += p * logf(p + 1e-10f);
  }
  __shared__ float red[256];
  red[t] = ps;
  __syncthreads();
  for (int st = 128; st; st >>= 1) { if (t < st) red[t] += red[t + st]; __syncthreads(); }
  if (t == 0) atomicAdd(&acc[1], expf(-red[0]) * (1.0f / (float)B_));
}

__global__ void k_final(const float* __restrict__ acc, float* __restrict__ out) {
  if (threadIdx.x == 0 && blockIdx.x == 0) {
    float L = acc[0] * (1.0f / 8388608.0f);   // B*S*D
    size_t base = (size_t)B_ * SP1_ * D_;
    out[base + 0] = acc[1];                   // perplexity (already mean over b)
    out[base + 1] = L;                        // e_latent_loss
    out[base + 2] = L;                        // q_latent_loss
    out[base + 3] = L + 0.25f * L;            // vq_loss
  }
}

// ---------------- workspace layout (bytes) ----------------
#define OFF_W0    0u
#define OFF_PROJ  16384u
#define OFF_ET    (OFF_PROJ + 2097152u)
#define OFF_EMBT  (OFF_ET + 2097152u)
#define OFF_POSB  (OFF_EMBT + 8388608u)
#define OFF_ESQ   (OFF_POSB + 16777216u)
#define OFF_PVAL  (OFF_ESQ + 65536u)
#define OFF_PIDX  (OFF_PVAL + 2097152u)
#define OFF_IDX   (OFF_PIDX + 2097152u)
#define OFF_HIST  (OFF_IDX + 131072u)
#define OFF_ACC   (OFF_HIST + 65536u)

extern "C" void kernel_launch(void* const* d_in, const int* in_sizes, int n_in,
                              void* d_out, int out_size, void* d_ws, size_t ws_size,
                              hipStream_t stream) {
  (void)in_sizes; (void)n_in; (void)out_size; (void)ws_size;
  const float* x    = (const float*)d_in[0];
  const float* E    = (const float*)d_in[1];
  const float* clsw = (const float*)d_in[2];
  const float* clsb = (const float*)d_in[3];
  float* out = (float*)d_out;

  char* ws = (char*)d_ws;
  float* w0   = (float*)(ws + OFF_W0);
  u16*   proj = (u16*)  (ws + OFF_PROJ);
  u16*   ET   = (u16*)  (ws + OFF_ET);
  u16*   embT = (u16*)  (ws + OFF_EMBT);
  u16*   posb = (u16*)  (ws + OFF_POSB);
  float* esq  = (float*)(ws + OFF_ESQ);
  float* pval = (float*)(ws + OFF_PVAL);
  int*   pidx = (int*)  (ws + OFF_PIDX);
  int*   idx  = (int*)  (ws + OFF_IDX);
  int*   hist = (int*)  (ws + OFF_HIST);
  float* acc  = (float*)(ws + OFF_ACC);

  hipMemsetAsync(esq, 0, 65536, stream);
  hipMemsetAsync(hist, 0, 65536, stream);
  hipMemsetAsync(acc, 0, 256, stream);

  k_cast_pos<<<8192, 256, 0, stream>>>(x, posb);
  k_w0<<<16, 256, 0, stream>>>(x, clsw, w0);
  k_softmax<<<B_ * D_, 256, 0, stream>>>(x, w0, clsb, proj);
  k_transpose_E<<<dim3(C_ / 32, R_ / 32), dim3(32, 8), 0, stream>>>(E, ET);
  k_gemm_emb<<<dim3(16, 2, B_), 256, 0, stream>>>(proj, ET, embT, esq);
  k_gemm_dist<<<dim3(16, 32, B_), 256, 0, stream>>>(posb, embT, esq, pval, pidx);
  k_reduce_idx<<<128, 256, 0, stream>>>(pval, pidx, idx);
  k_gather<<<dim3(32, B_), 256, 0, stream>>>(x, embT, idx, out, acc);
  k_hist<<<128, 256, 0, stream>>>(idx, hist);
  k_perp<<<B_, 256, 0, stream>>>(hist, acc);
  k_final<<<1, 64, 0, stream>>>(acc, out);
}

// Round 2
// 228.204 us; speedup vs baseline: 1.0244x; 1.0244x over previous
//
#include <hip/hip_runtime.h>
#include <hip/hip_bf16.h>
#include <stdint.h>

#define B_   8
#define S_   4096
#define SP1_ 4097
#define D_   256
#define R_   512
#define C_   2048

typedef __attribute__((ext_vector_type(8))) short bf16x8;
typedef __attribute__((ext_vector_type(4))) float f32x4;
typedef unsigned short u16;

__device__ __forceinline__ u16 f2bf(float f) {
  __hip_bfloat16 h = __float2bfloat16(f);
  return *(u16*)&h;
}
__device__ __forceinline__ float bf2f(u16 u) {
  __hip_bfloat16 h = *(__hip_bfloat16*)&u;
  return __bfloat162float(h);
}

// async global->LDS, 16B per lane; LDS dst = wave-uniform base + lane*16
__device__ __forceinline__ void gload16(const u16* g, u16* l) {
  __builtin_amdgcn_global_load_lds(
      (const __attribute__((address_space(1))) uint32_t*)g,
      (__attribute__((address_space(3))) uint32_t*)l, 16, 0, 0);
}

// ---------------- cast pos tokens (x[:,1:,:]) to bf16, layout (B,S,D) ----------------
__global__ void k_cast_pos(const float* __restrict__ x, u16* __restrict__ posb) {
  int i = blockIdx.x * 256 + threadIdx.x;     // B*S*D/4 threads
  int g = i << 2;
  int b = g >> 20;
  int rem = g & 1048575;
  const float4 v = *(const float4*)(x + (size_t)b * SP1_ * D_ + D_ + rem);
  ushort4 u;
  u.x = f2bf(v.x); u.y = f2bf(v.y); u.z = f2bf(v.z); u.w = f2bf(v.w);
  *(ushort4*)(posb + g) = u;
}

// ---------------- w0[b,r] = sum_d cls[b,d] * cls_w[d,r]  (64 blocks) ----------------
__global__ void k_w0(const float* __restrict__ x, const float* __restrict__ clsw,
                     float* __restrict__ w0) {
  int blk = blockIdx.x;                       // b*8 + rc
  int b = blk >> 3, rc = blk & 7;
  int t = threadIdx.x;
  int r = rc * 64 + (t & 63);
  int dg = t >> 6;                            // 0..3
  const float* cls = x + (size_t)b * SP1_ * D_;
  float a = 0.f;
  for (int d = dg * 64; d < dg * 64 + 64; d++) a += cls[d] * clsw[d * R_ + r];
  __shared__ float red[256];
  red[t] = a;
  __syncthreads();
  if (t < 64) w0[b * R_ + r] = red[t] + red[t + 64] + red[t + 128] + red[t + 192];
}

// ---------------- proj[b,d,r] = softmax_r(cls[b,d]*w0[b,r] + cls_b[r]), bf16 ----------------
__global__ void k_softmax(const float* __restrict__ x, const float* __restrict__ w0,
                          const float* __restrict__ clsb, u16* __restrict__ proj) {
  int bd = blockIdx.x;                        // B*D = 2048 blocks
  int b = bd >> 8, d = bd & 255;
  float c = x[(size_t)b * SP1_ * D_ + d];
  int t = threadIdx.x;
  float l0 = c * w0[b * R_ + t] + clsb[t];
  float l1 = c * w0[b * R_ + t + 256] + clsb[t + 256];
  __shared__ float red[256];
  red[t] = fmaxf(l0, l1);
  __syncthreads();
  for (int st = 128; st; st >>= 1) { if (t < st) red[t] = fmaxf(red[t], red[t + st]); __syncthreads(); }
  float m = red[0];
  __syncthreads();
  float e0 = expf(l0 - m), e1 = expf(l1 - m);
  red[t] = e0 + e1;
  __syncthreads();
  for (int st = 128; st; st >>= 1) { if (t < st) red[t] += red[t + st]; __syncthreads(); }
  float inv = 1.0f / red[0];
  size_t base = ((size_t)b * D_ + d) * R_;
  proj[base + t]       = f2bf(e0 * inv);
  proj[base + t + 256] = f2bf(e1 * inv);
}

// ---------------- ET[c,r] = bf16(E[r,c])  (512x2048 -> 2048x512) ----------------
__global__ void k_transpose_E(const float* __restrict__ E, u16* __restrict__ ET) {
  __shared__ float tile[32][33];
  int c0 = blockIdx.x * 32, r0 = blockIdx.y * 32;
  int tx = threadIdx.x, ty = threadIdx.y;     // 32 x 8
  #pragma unroll
  for (int i = 0; i < 4; i++) {
    int r = r0 + ty + i * 8;
    tile[ty + i * 8][tx] = E[(size_t)r * C_ + c0 + tx];
  }
  __syncthreads();
  #pragma unroll
  for (int i = 0; i < 4; i++) {
    int c = c0 + ty + i * 8;
    ET[(size_t)c * R_ + r0 + tx] = f2bf(tile[tx][ty + i * 8]);
  }
}

// ---------------- emb GEMM (64x128 tile): embT[b,c,d], esq partials ----------------
__global__ __launch_bounds__(256) void k_gemm_emb(const u16* __restrict__ proj,
                                                  const u16* __restrict__ ET,
                                                  u16* __restrict__ embT,
                                                  float* __restrict__ esq) {
  int ct = blockIdx.x, mt = blockIdx.y, b = blockIdx.z;
  int n0 = ct * 128, m0 = mt * 64;
  const u16* A  = proj + (size_t)b * D_ * R_;   // D x R
  const u16* Bt = ET;                           // C x R
  __shared__ u16 tA[2048], tB[4096];            // 64x32, 128x32
  int tid = threadIdx.x;
  int wv = tid >> 6, lane = tid & 63, ln = lane & 15, qd = lane >> 4;
  int srow = lane >> 2, scol = (lane & 3) * 8;
  const u16* gA0 = A  + (size_t)(m0 + wv * 16 + srow) * R_ + scol;
  const u16* gB0 = Bt + (size_t)(n0 + wv * 16 + srow) * R_ + scol;
  const u16* gB1 = gB0 + (size_t)64 * R_;
  u16* lA0 = &tA[(wv * 16) * 32];
  u16* lB0 = &tB[(wv * 16) * 32];
  u16* lB1 = &tB[(64 + wv * 16) * 32];
  f32x4 acc[8];
  #pragma unroll
  for (int nf = 0; nf < 8; nf++) acc[nf] = (f32x4){0.f, 0.f, 0.f, 0.f};

  for (int kk = 0; kk < R_; kk += 32) {
    __syncthreads();
    gload16(gA0 + kk, lA0);
    gload16(gB0 + kk, lB0);
    gload16(gB1 + kk, lB1);
    __syncthreads();
    bf16x8 af = *(bf16x8*)&tA[(wv * 16 + ln) * 32 + qd * 8];
    bf16x8 bfr[8];
    #pragma unroll
    for (int nf = 0; nf < 8; nf++) bfr[nf] = *(bf16x8*)&tB[(nf * 16 + ln) * 32 + qd * 8];
    #pragma unroll
    for (int nf = 0; nf < 8; nf++)
      acc[nf] = __builtin_amdgcn_mfma_f32_16x16x32_bf16(af, bfr[nf], acc[nf], 0, 0, 0);
  }
  // epilogue: C[m=d][n=c]; write embT[c,d], reduce esq over qd then atomic
  #pragma unroll
  for (int nf = 0; nf < 8; nf++) {
    int c = n0 + nf * 16 + ln;
    int dbase = m0 + wv * 16 + qd * 4;
    f32x4 v = acc[nf];
    ushort4 u;
    u.x = f2bf(v[0]); u.y = f2bf(v[1]); u.z = f2bf(v[2]); u.w = f2bf(v[3]);
    *(ushort4*)&embT[((size_t)b * C_ + c) * D_ + dbase] = u;
    float ss = v[0]*v[0] + v[1]*v[1] + v[2]*v[2] + v[3]*v[3];
    ss += __shfl_xor(ss, 16);
    ss += __shfl_xor(ss, 32);
    if (qd == 0) atomicAdd(&esq[b * C_ + c], ss);
  }
}

// ---------------- dist GEMM (128x128) + per-tile argmin partials ----------------
__global__ __launch_bounds__(256) void k_gemm_dist(const u16* __restrict__ posb,
                                                   const u16* __restrict__ embT,
                                                   const float* __restrict__ esq,
                                                   float* __restrict__ pval,
                                                   int* __restrict__ pidx) {
  int ct = blockIdx.x, st = blockIdx.y, b = blockIdx.z;
  int n0 = ct * 128, m0 = st * 128;
  const u16* A  = posb + (size_t)b * S_ * D_;   // S x D
  const u16* Bt = embT + (size_t)b * C_ * D_;   // C x D
  __shared__ u16 tA[4096], tB[4096];
  __shared__ float sh_esq[128];
  int tid = threadIdx.x;
  if (tid < 128) sh_esq[tid] = esq[b * C_ + n0 + tid];
  int wv = tid >> 6, lane = tid & 63, ln = lane & 15, qd = lane >> 4;
  int srow = lane >> 2, scol = (lane & 3) * 8;
  const u16* gA0 = A  + (size_t)(m0 + wv * 16 + srow) * D_ + scol;
  const u16* gA1 = gA0 + (size_t)64 * D_;
  const u16* gB0 = Bt + (size_t)(n0 + wv * 16 + srow) * D_ + scol;
  const u16* gB1 = gB0 + (size_t)64 * D_;
  u16* lA0 = &tA[(wv * 16) * 32];
  u16* lA1 = &tA[(64 + wv * 16) * 32];
  u16* lB0 = &tB[(wv * 16) * 32];
  u16* lB1 = &tB[(64 + wv * 16) * 32];
  f32x4 acc[2][8];
  #pragma unroll
  for (int mf = 0; mf < 2; mf++)
    #pragma unroll
    for (int nf = 0; nf < 8; nf++) acc[mf][nf] = (f32x4){0.f, 0.f, 0.f, 0.f};

  for (int kk = 0; kk < D_; kk += 32) {
    __syncthreads();
    gload16(gA0 + kk, lA0);
    gload16(gA1 + kk, lA1);
    gload16(gB0 + kk, lB0);
    gload16(gB1 + kk, lB1);
    __syncthreads();
    bf16x8 af[2], bfr[8];
    #pragma unroll
    for (int mf = 0; mf < 2; mf++) af[mf] = *(bf16x8*)&tA[(wv * 32 + mf * 16 + ln) * 32 + qd * 8];
    #pragma unroll
    for (int nf = 0; nf < 8; nf++) bfr[nf] = *(bf16x8*)&tB[(nf * 16 + ln) * 32 + qd * 8];
    #pragma unroll
    for (int mf = 0; mf < 2; mf++)
      #pragma unroll
      for (int nf = 0; nf < 8; nf++)
        acc[mf][nf] = __builtin_amdgcn_mfma_f32_16x16x32_bf16(af[mf], bfr[nf], acc[mf][nf], 0, 0, 0);
  }
  // per-row argmin of score = esq[c] - 2*dot over this tile's 128 cols
  #pragma unroll
  for (int mf = 0; mf < 2; mf++) {
    #pragma unroll
    for (int reg = 0; reg < 4; reg++) {
      float bv = 3.4e38f; int bc = 0;
      #pragma unroll
      for (int nf = 0; nf < 8; nf++) {
        int c = nf * 16 + ln;
        float sc = sh_esq[c] - 2.0f * acc[mf][nf][reg];
        if (sc < bv || (sc == bv && c < bc)) { bv = sc; bc = c; }
      }
      #pragma unroll
      for (int off = 1; off < 16; off <<= 1) {
        float ov = __shfl_xor(bv, off);
        int   oc = __shfl_xor(bc, off);
        if (ov < bv || (ov == bv && oc < bc)) { bv = ov; bc = oc; }
      }
      if (ln == 0) {
        int s = m0 + wv * 32 + mf * 16 + qd * 4 + reg;
        size_t o = ((size_t)b * S_ + s) * 16 + ct;
        pval[o] = bv;
        pidx[o] = n0 + bc;
      }
    }
  }
}

// ---------------- reduce 16 tile-partials -> final index + histogram ----------------
__global__ void k_reduce_idx(const float* __restrict__ pval, const int* __restrict__ pidx,
                             int* __restrict__ idx, int* __restrict__ hist) {
  int i = blockIdx.x * 256 + threadIdx.x;     // < B*S
  const float* pv = pval + (size_t)i * 16;
  const int*   pi = pidx + (size_t)i * 16;
  float bv = pv[0]; int bi = pi[0];
  #pragma unroll
  for (int j = 1; j < 16; j++) {
    float v = pv[j]; int ix = pi[j];
    if (v < bv || (v == bv && ix < bi)) { bv = v; bi = ix; }
  }
  idx[i] = bi;
  atomicAdd(&hist[(i >> 12) * C_ + bi], 1);
}

// ---------------- gather quantized, write output, accumulate SSE; copy cls row ----------------
__global__ void k_gather(const float* __restrict__ x, const u16* __restrict__ embT,
                         const int* __restrict__ idx, float* __restrict__ out,
                         float* __restrict__ acc) {
  int b = blockIdx.y;
  int sg = blockIdx.x * 32;                   // 128 x 8 blocks
  int t = threadIdx.x;
  int sl = t >> 6;                            // 0..3
  int d4 = (t & 63) << 2;
  size_t xb = (size_t)b * SP1_ * D_;
  if (blockIdx.x == 0 && sl == 0)
    *(float4*)(out + xb + d4) = *(const float4*)(x + xb + d4);  // cls passthrough
  const u16* eb = embT + (size_t)b * C_ * D_;
  float lsum = 0.f;
  #pragma unroll
  for (int j = 0; j < 8; j++) {
    int s = sg + j * 4 + sl;
    int ix = idx[b * S_ + s];
    ushort4 q4 = *(const ushort4*)(eb + (size_t)ix * D_ + d4);
    size_t o = xb + (size_t)(s + 1) * D_ + d4;
    float4 p = *(const float4*)(x + o);
    float4 q;
    q.x = bf2f(q4.x); q.y = bf2f(q4.y); q.z = bf2f(q4.z); q.w = bf2f(q4.w);
    *(float4*)(out + o) = q;
    float e0 = q.x - p.x, e1 = q.y - p.y, e2 = q.z - p.z, e3 = q.w - p.w;
    lsum += e0 * e0 + e1 * e1 + e2 * e2 + e3 * e3;
  }
  __shared__ float red[256];
  red[t] = lsum;
  __syncthreads();
  for (int st = 128; st; st >>= 1) { if (t < st) red[t] += red[t + st]; __syncthreads(); }
  if (t == 0) atomicAdd(&acc[0], red[0]);
}

// ---------------- perplexity ----------------
__global__ void k_perp(const int* __restrict__ hist, float* __restrict__ acc) {
  int b = blockIdx.x, t = threadIdx.x;
  float ps = 0.f;
  for (int c = t; c < C_; c += 256) {
    float p = (float)hist[b * C_ + c] * (1.0f / (float)S_);
    ps += p * logf(p + 1e-10f);
  }
  __shared__ float red[256];
  red[t] = ps;
  __syncthreads();
  for (int st = 128; st; st >>= 1) { if (t < st) red[t] += red[t + st]; __syncthreads(); }
  if (t == 0) atomicAdd(&acc[1], expf(-red[0]) * (1.0f / (float)B_));
}

__global__ void k_final(const float* __restrict__ acc, float* __restrict__ out) {
  if (threadIdx.x == 0 && blockIdx.x == 0) {
    float L = acc[0] * (1.0f / 8388608.0f);   // B*S*D
    size_t base = (size_t)B_ * SP1_ * D_;
    out[base + 0] = acc[1];                   // perplexity
    out[base + 1] = L;                        // e_latent_loss
    out[base + 2] = L;                        // q_latent_loss
    out[base + 3] = L + 0.25f * L;            // vq_loss
  }
}

// ---------------- workspace layout (bytes); esq/hist/acc contiguous for one memset ----------------
#define OFF_W0    0u
#define OFF_ESQ   16384u
#define OFF_HIST  (OFF_ESQ + 65536u)
#define OFF_ACC   (OFF_HIST + 65536u)
#define OFF_PROJ  (OFF_ACC + 256u)
#define OFF_ET    (OFF_PROJ + 2097152u)
#define OFF_EMBT  (OFF_ET + 2097152u)
#define OFF_POSB  (OFF_EMBT + 8388608u)
#define OFF_PVAL  (OFF_POSB + 16777216u)
#define OFF_PIDX  (OFF_PVAL + 2097152u)
#define OFF_IDX   (OFF_PIDX + 2097152u)

extern "C" void kernel_launch(void* const* d_in, const int* in_sizes, int n_in,
                              void* d_out, int out_size, void* d_ws, size_t ws_size,
                              hipStream_t stream) {
  (void)in_sizes; (void)n_in; (void)out_size; (void)ws_size;
  const float* x    = (const float*)d_in[0];
  const float* E    = (const float*)d_in[1];
  const float* clsw = (const float*)d_in[2];
  const float* clsb = (const float*)d_in[3];
  float* out = (float*)d_out;

  char* ws = (char*)d_ws;
  float* w0   = (float*)(ws + OFF_W0);
  float* esq  = (float*)(ws + OFF_ESQ);
  int*   hist = (int*)  (ws + OFF_HIST);
  float* acc  = (float*)(ws + OFF_ACC);
  u16*   proj = (u16*)  (ws + OFF_PROJ);
  u16*   ET   = (u16*)  (ws + OFF_ET);
  u16*   embT = (u16*)  (ws + OFF_EMBT);
  u16*   posb = (u16*)  (ws + OFF_POSB);
  float* pval = (float*)(ws + OFF_PVAL);
  int*   pidx = (int*)  (ws + OFF_PIDX);
  int*   idx  = (int*)  (ws + OFF_IDX);

  hipMemsetAsync(esq, 0, 65536u + 65536u + 256u, stream);

  k_cast_pos<<<8192, 256, 0, stream>>>(x, posb);
  k_w0<<<64, 256, 0, stream>>>(x, clsw, w0);
  k_softmax<<<B_ * D_, 256, 0, stream>>>(x, w0, clsb, proj);
  k_transpose_E<<<dim3(C_ / 32, R_ / 32), dim3(32, 8), 0, stream>>>(E, ET);
  k_gemm_emb<<<dim3(16, 4, B_), 256, 0, stream>>>(proj, ET, embT, esq);
  k_gemm_dist<<<dim3(16, 32, B_), 256, 0, stream>>>(posb, embT, esq, pval, pidx);
  k_reduce_idx<<<128, 256, 0, stream>>>(pval, pidx, idx, hist);
  k_gather<<<dim3(128, B_), 256, 0, stream>>>(x, embT, idx, out, acc);
  k_perp<<<B_, 256, 0, stream>>>(hist, acc);
  k_final<<<1, 64, 0, stream>>>(acc, out);
}

// Round 3
// 218.028 us; speedup vs baseline: 1.0722x; 1.0467x over previous
//
#include <hip/hip_runtime.h>
#include <hip/hip_bf16.h>
#include <stdint.h>

#define B_   8
#define S_   4096
#define SP1_ 4097
#define D_   256
#define R_   512
#define C_   2048

typedef __attribute__((ext_vector_type(8))) short bf16x8;
typedef __attribute__((ext_vector_type(4))) float f32x4;
typedef unsigned short u16;

__device__ __forceinline__ u16 f2bf(float f) {
  __hip_bfloat16 h = __float2bfloat16(f);
  return *(u16*)&h;
}
__device__ __forceinline__ float bf2f(u16 u) {
  __hip_bfloat16 h = *(__hip_bfloat16*)&u;
  return __bfloat162float(h);
}

// async global->LDS, 16B per lane; LDS dst = wave-uniform base + lane*16
__device__ __forceinline__ void gload16(const u16* g, u16* l) {
  __builtin_amdgcn_global_load_lds(
      (const __attribute__((address_space(1))) uint32_t*)g,
      (__attribute__((address_space(3))) uint32_t*)l, 16, 0, 0);
}

// ---------------- cast pos tokens to bf16 + per-row q_sq ----------------
// block = 4 waves, one s-row per wave (64 lanes x 4 floats = 256 = D)
__global__ void k_cast_pos(const float* __restrict__ x, u16* __restrict__ posb,
                           float* __restrict__ qsq) {
  int wv = threadIdx.x >> 6, lane = threadIdx.x & 63;
  int row = blockIdx.x * 4 + wv;              // [0, B*S)
  int b = row >> 12, s = row & 4095;
  const float4 v = *(const float4*)(x + (size_t)b * SP1_ * D_ + (size_t)(s + 1) * D_ + lane * 4);
  ushort4 u;
  u.x = f2bf(v.x); u.y = f2bf(v.y); u.z = f2bf(v.z); u.w = f2bf(v.w);
  *(ushort4*)(posb + (size_t)row * D_ + lane * 4) = u;
  float ss = v.x * v.x + v.y * v.y + v.z * v.z + v.w * v.w;
  #pragma unroll
  for (int off = 1; off < 64; off <<= 1) ss += __shfl_xor(ss, off);
  if (lane == 0) qsq[row] = ss;
}

// ---------------- w0[b,r] = sum_d cls[b,d] * cls_w[d,r]  (64 blocks) ----------------
__global__ void k_w0(const float* __restrict__ x, const float* __restrict__ clsw,
                     float* __restrict__ w0) {
  int blk = blockIdx.x;                       // b*8 + rc
  int b = blk >> 3, rc = blk & 7;
  int t = threadIdx.x;
  int r = rc * 64 + (t & 63);
  int dg = t >> 6;                            // 0..3
  const float* cls = x + (size_t)b * SP1_ * D_;
  float a = 0.f;
  for (int d = dg * 64; d < dg * 64 + 64; d++) a += cls[d] * clsw[d * R_ + r];
  __shared__ float red[256];
  red[t] = a;
  __syncthreads();
  if (t < 64) w0[b * R_ + r] = red[t] + red[t + 64] + red[t + 128] + red[t + 192];
}

// ---------------- proj[b,d,r] = softmax_r(cls[b,d]*w0[b,r] + cls_b[r]), bf16 ----------------
__global__ void k_softmax(const float* __restrict__ x, const float* __restrict__ w0,
                          const float* __restrict__ clsb, u16* __restrict__ proj) {
  int bd = blockIdx.x;                        // B*D = 2048 blocks
  int b = bd >> 8, d = bd & 255;
  float c = x[(size_t)b * SP1_ * D_ + d];
  int t = threadIdx.x;
  float l0 = c * w0[b * R_ + t] + clsb[t];
  float l1 = c * w0[b * R_ + t + 256] + clsb[t + 256];
  __shared__ float red[256];
  red[t] = fmaxf(l0, l1);
  __syncthreads();
  for (int st = 128; st; st >>= 1) { if (t < st) red[t] = fmaxf(red[t], red[t + st]); __syncthreads(); }
  float m = red[0];
  __syncthreads();
  float e0 = expf(l0 - m), e1 = expf(l1 - m);
  red[t] = e0 + e1;
  __syncthreads();
  for (int st = 128; st; st >>= 1) { if (t < st) red[t] += red[t + st]; __syncthreads(); }
  float inv = 1.0f / red[0];
  size_t base = ((size_t)b * D_ + d) * R_;
  proj[base + t]       = f2bf(e0 * inv);
  proj[base + t + 256] = f2bf(e1 * inv);
}

// ---------------- ET[c,r] = bf16(E[r,c]) ----------------
__global__ void k_transpose_E(const float* __restrict__ E, u16* __restrict__ ET) {
  __shared__ float tile[32][33];
  int c0 = blockIdx.x * 32, r0 = blockIdx.y * 32;
  int tx = threadIdx.x, ty = threadIdx.y;     // 32 x 8
  #pragma unroll
  for (int i = 0; i < 4; i++) {
    int r = r0 + ty + i * 8;
    tile[ty + i * 8][tx] = E[(size_t)r * C_ + c0 + tx];
  }
  __syncthreads();
  #pragma unroll
  for (int i = 0; i < 4; i++) {
    int c = c0 + ty + i * 8;
    ET[(size_t)c * R_ + r0 + tx] = f2bf(tile[tx][ty + i * 8]);
  }
}

// XOR slot swizzle: data (row r, 16B-chunk c) lives at slot chunk c ^ (r&3) ^ ((r>>2)&3).
// Writer lane L (srow=L>>2) fetches global chunk (L&3)^(srow&3)^((srow>>2)&3) so the
// fixed lane->slot DMA of global_load_lds lands it swizzled; readers XOR the same term.
// Result: every 16-lane phase of a ds_read_b128 covers all 8 bank-quads exactly 2x (free).

// ---------------- emb GEMM (64x128 tile): embT[b,c,d], esq ----------------
__global__ __launch_bounds__(256) void k_gemm_emb(const u16* __restrict__ proj,
                                                  const u16* __restrict__ ET,
                                                  u16* __restrict__ embT,
                                                  float* __restrict__ esq) {
  int ct = blockIdx.x, mt = blockIdx.y, b = blockIdx.z;
  int n0 = ct * 128, m0 = mt * 64;
  const u16* A  = proj + (size_t)b * D_ * R_;   // D x R
  const u16* Bt = ET;                           // C x R
  __shared__ u16 tA[2048], tB[4096];            // 64x32, 128x32
  int tid = threadIdx.x;
  int wv = tid >> 6, lane = tid & 63, ln = lane & 15, qd = lane >> 4;
  int srow = lane >> 2;
  int scol = (((lane & 3) ^ (srow & 3) ^ ((srow >> 2) & 3))) * 8;
  const u16* gA0 = A  + (size_t)(m0 + wv * 16 + srow) * R_ + scol;
  const u16* gB0 = Bt + (size_t)(n0 + wv * 16 + srow) * R_ + scol;
  const u16* gB1 = gB0 + (size_t)64 * R_;
  u16* lA0 = &tA[(wv * 16) * 32];
  u16* lB0 = &tB[(wv * 16) * 32];
  u16* lB1 = &tB[(64 + wv * 16) * 32];
  int cs8 = ((qd ^ (ln & 3) ^ ((ln >> 2) & 3))) * 8;   // reader swizzled chunk offset
  f32x4 acc[8];
  #pragma unroll
  for (int nf = 0; nf < 8; nf++) acc[nf] = (f32x4){0.f, 0.f, 0.f, 0.f};

  for (int kk = 0; kk < R_; kk += 32) {
    __syncthreads();
    gload16(gA0 + kk, lA0);
    gload16(gB0 + kk, lB0);
    gload16(gB1 + kk, lB1);
    __syncthreads();
    bf16x8 af = *(bf16x8*)&tA[(wv * 16 + ln) * 32 + cs8];
    bf16x8 bfr[8];
    #pragma unroll
    for (int nf = 0; nf < 8; nf++) bfr[nf] = *(bf16x8*)&tB[(nf * 16 + ln) * 32 + cs8];
    #pragma unroll
    for (int nf = 0; nf < 8; nf++)
      acc[nf] = __builtin_amdgcn_mfma_f32_16x16x32_bf16(af, bfr[nf], acc[nf], 0, 0, 0);
  }
  #pragma unroll
  for (int nf = 0; nf < 8; nf++) {
    int c = n0 + nf * 16 + ln;
    int dbase = m0 + wv * 16 + qd * 4;
    f32x4 v = acc[nf];
    ushort4 u;
    u.x = f2bf(v[0]); u.y = f2bf(v[1]); u.z = f2bf(v[2]); u.w = f2bf(v[3]);
    *(ushort4*)&embT[((size_t)b * C_ + c) * D_ + dbase] = u;
    float ss = v[0]*v[0] + v[1]*v[1] + v[2]*v[2] + v[3]*v[3];
    ss += __shfl_xor(ss, 16);
    ss += __shfl_xor(ss, 32);
    if (qd == 0) atomicAdd(&esq[b * C_ + c], ss);
  }
}

// ---------------- dist GEMM (128x128) + per-tile argmin partials ----------------
__global__ __launch_bounds__(256) void k_gemm_dist(const u16* __restrict__ posb,
                                                   const u16* __restrict__ embT,
                                                   const float* __restrict__ esq,
                                                   float* __restrict__ pval,
                                                   int* __restrict__ pidx) {
  int ct = blockIdx.x, st = blockIdx.y, b = blockIdx.z;
  int n0 = ct * 128, m0 = st * 128;
  const u16* A  = posb + (size_t)b * S_ * D_;   // S x D
  const u16* Bt = embT + (size_t)b * C_ * D_;   // C x D
  __shared__ u16 tA[4096], tB[4096];
  __shared__ float sh_esq[128];
  int tid = threadIdx.x;
  if (tid < 128) sh_esq[tid] = esq[b * C_ + n0 + tid];
  int wv = tid >> 6, lane = tid & 63, ln = lane & 15, qd = lane >> 4;
  int srow = lane >> 2;
  int scol = (((lane & 3) ^ (srow & 3) ^ ((srow >> 2) & 3))) * 8;
  const u16* gA0 = A  + (size_t)(m0 + wv * 16 + srow) * D_ + scol;
  const u16* gA1 = gA0 + (size_t)64 * D_;
  const u16* gB0 = Bt + (size_t)(n0 + wv * 16 + srow) * D_ + scol;
  const u16* gB1 = gB0 + (size_t)64 * D_;
  u16* lA0 = &tA[(wv * 16) * 32];
  u16* lA1 = &tA[(64 + wv * 16) * 32];
  u16* lB0 = &tB[(wv * 16) * 32];
  u16* lB1 = &tB[(64 + wv * 16) * 32];
  int cs8 = ((qd ^ (ln & 3) ^ ((ln >> 2) & 3))) * 8;
  f32x4 acc[2][8];
  #pragma unroll
  for (int mf = 0; mf < 2; mf++)
    #pragma unroll
    for (int nf = 0; nf < 8; nf++) acc[mf][nf] = (f32x4){0.f, 0.f, 0.f, 0.f};

  for (int kk = 0; kk < D_; kk += 32) {
    __syncthreads();
    gload16(gA0 + kk, lA0);
    gload16(gA1 + kk, lA1);
    gload16(gB0 + kk, lB0);
    gload16(gB1 + kk, lB1);
    __syncthreads();
    bf16x8 af[2], bfr[8];
    #pragma unroll
    for (int mf = 0; mf < 2; mf++) af[mf] = *(bf16x8*)&tA[(wv * 32 + mf * 16 + ln) * 32 + cs8];
    #pragma unroll
    for (int nf = 0; nf < 8; nf++) bfr[nf] = *(bf16x8*)&tB[(nf * 16 + ln) * 32 + cs8];
    #pragma unroll
    for (int mf = 0; mf < 2; mf++)
      #pragma unroll
      for (int nf = 0; nf < 8; nf++)
        acc[mf][nf] = __builtin_amdgcn_mfma_f32_16x16x32_bf16(af[mf], bfr[nf], acc[mf][nf], 0, 0, 0);
  }
  #pragma unroll
  for (int mf = 0; mf < 2; mf++) {
    #pragma unroll
    for (int reg = 0; reg < 4; reg++) {
      float bv = 3.4e38f; int bc = 0;
      #pragma unroll
      for (int nf = 0; nf < 8; nf++) {
        int c = nf * 16 + ln;
        float sc = sh_esq[c] - 2.0f * acc[mf][nf][reg];
        if (sc < bv || (sc == bv && c < bc)) { bv = sc; bc = c; }
      }
      #pragma unroll
      for (int off = 1; off < 16; off <<= 1) {
        float ov = __shfl_xor(bv, off);
        int   oc = __shfl_xor(bc, off);
        if (ov < bv || (ov == bv && oc < bc)) { bv = ov; bc = oc; }
      }
      if (ln == 0) {
        int s = m0 + wv * 32 + mf * 16 + qd * 4 + reg;
        size_t o = ((size_t)b * S_ + s) * 16 + ct;
        pval[o] = bv;
        pidx[o] = n0 + bc;
      }
    }
  }
}

// ---------------- reduce partials -> index + histogram + SSE (bv + qsq) ----------------
__global__ void k_reduce_idx(const float* __restrict__ pval, const int* __restrict__ pidx,
                             const float* __restrict__ qsq, int* __restrict__ idx,
                             int* __restrict__ hist, float* __restrict__ acc) {
  int t = threadIdx.x;
  int i = blockIdx.x * 256 + t;               // < B*S
  const float* pv = pval + (size_t)i * 16;
  const int*   pi = pidx + (size_t)i * 16;
  float bv = pv[0]; int bi = pi[0];
  #pragma unroll
  for (int j = 1; j < 16; j++) {
    float v = pv[j]; int ix = pi[j];
    if (v < bv || (v == bv && ix < bi)) { bv = v; bi = ix; }
  }
  idx[i] = bi;
  atomicAdd(&hist[(i >> 12) * C_ + bi], 1);
  // SSE contribution of row i: min score (= e_sq - 2*dot) + ||pos||^2
  float sse = bv + qsq[i];
  #pragma unroll
  for (int off = 1; off < 64; off <<= 1) sse += __shfl_xor(sse, off);
  __shared__ float red[4];
  if ((t & 63) == 0) red[t >> 6] = sse;
  __syncthreads();
  if (t == 0) atomicAdd(&acc[0], red[0] + red[1] + red[2] + red[3]);
}

// ---------------- gather quantized rows -> out (no x pos re-read) ----------------
__global__ void k_gather(const float* __restrict__ x, const u16* __restrict__ embT,
                         const int* __restrict__ idx, float* __restrict__ out) {
  int b = blockIdx.y;
  int wv = threadIdx.x >> 6, lane = threadIdx.x & 63;
  int s = blockIdx.x * 4 + wv;                // 1024 x-blocks
  size_t xb = (size_t)b * SP1_ * D_;
  if (blockIdx.x == 0 && wv == 0)
    *(float4*)(out + xb + lane * 4) = *(const float4*)(x + xb + lane * 4);  // cls passthrough
  int ix = idx[b * S_ + s];
  ushort4 q4 = *(const ushort4*)(embT + ((size_t)b * C_ + ix) * D_ + lane * 4);
  float4 q;
  q.x = bf2f(q4.x); q.y = bf2f(q4.y); q.z = bf2f(q4.z); q.w = bf2f(q4.w);
  *(float4*)(out + xb + (size_t)(s + 1) * D_ + lane * 4) = q;
}

// ---------------- perplexity + final scalars (fused; last block writes) ----------------
__global__ void k_perp(const int* __restrict__ hist, float* __restrict__ acc,
                       float* __restrict__ out) {
  int b = blockIdx.x, t = threadIdx.x;
  float ps = 0.f;
  for (int c = t; c < C_; c += 256) {
    float p = (float)hist[b * C_ + c] * (1.0f / (float)S_);
    ps += p * logf(p + 1e-10f);
  }
  __shared__ float red[256];
  red[t] = ps;
  __syncthreads();
  for (int st = 128; st; st >>= 1) { if (t < st) red[t] += red[t + st]; __syncthreads(); }
  if (t == 0) {
    atomicAdd(&acc[1], expf(-red[0]) * (1.0f / (float)B_));
    __threadfence();
    int done = atomicAdd((int*)acc + 2, 1);
    if (done == B_ - 1) {
      float P = atomicAdd(&acc[1], 0.0f);     // device-scope coherent read
      float SSE = atomicAdd(&acc[0], 0.0f);
      float L = SSE * (1.0f / 8388608.0f);    // / (B*S*D)
      size_t base = (size_t)B_ * SP1_ * D_;
      out[base + 0] = P;
      out[base + 1] = L;
      out[base + 2] = L;
      out[base + 3] = L + 0.25f * L;
    }
  }
}

// ---------------- workspace layout (bytes); esq/hist/acc contiguous for one memset ----------------
#define OFF_W0    0u
#define OFF_ESQ   16384u
#define OFF_HIST  (OFF_ESQ + 65536u)
#define OFF_ACC   (OFF_HIST + 65536u)
#define OFF_PROJ  (OFF_ACC + 256u)
#define OFF_ET    (OFF_PROJ + 2097152u)
#define OFF_EMBT  (OFF_ET + 2097152u)
#define OFF_POSB  (OFF_EMBT + 8388608u)
#define OFF_PVAL  (OFF_POSB + 16777216u)
#define OFF_PIDX  (OFF_PVAL + 2097152u)
#define OFF_IDX   (OFF_PIDX + 2097152u)
#define OFF_QSQ   (OFF_IDX + 131072u)

extern "C" void kernel_launch(void* const* d_in, const int* in_sizes, int n_in,
                              void* d_out, int out_size, void* d_ws, size_t ws_size,
                              hipStream_t stream) {
  (void)in_sizes; (void)n_in; (void)out_size; (void)ws_size;
  const float* x    = (const float*)d_in[0];
  const float* E    = (const float*)d_in[1];
  const float* clsw = (const float*)d_in[2];
  const float* clsb = (const float*)d_in[3];
  float* out = (float*)d_out;

  char* ws = (char*)d_ws;
  float* w0   = (float*)(ws + OFF_W0);
  float* esq  = (float*)(ws + OFF_ESQ);
  int*   hist = (int*)  (ws + OFF_HIST);
  float* acc  = (float*)(ws + OFF_ACC);
  u16*   proj = (u16*)  (ws + OFF_PROJ);
  u16*   ET   = (u16*)  (ws + OFF_ET);
  u16*   embT = (u16*)  (ws + OFF_EMBT);
  u16*   posb = (u16*)  (ws + OFF_POSB);
  float* pval = (float*)(ws + OFF_PVAL);
  int*   pidx = (int*)  (ws + OFF_PIDX);
  int*   idx  = (int*)  (ws + OFF_IDX);
  float* qsq  = (float*)(ws + OFF_QSQ);

  hipMemsetAsync(esq, 0, 65536u + 65536u + 256u, stream);

  k_cast_pos<<<8192, 256, 0, stream>>>(x, posb, qsq);
  k_w0<<<64, 256, 0, stream>>>(x, clsw, w0);
  k_softmax<<<B_ * D_, 256, 0, stream>>>(x, w0, clsb, proj);
  k_transpose_E<<<dim3(C_ / 32, R_ / 32), dim3(32, 8), 0, stream>>>(E, ET);
  k_gemm_emb<<<dim3(16, 4, B_), 256, 0, stream>>>(proj, ET, embT, esq);
  k_gemm_dist<<<dim3(16, 32, B_), 256, 0, stream>>>(posb, embT, esq, pval, pidx);
  k_reduce_idx<<<128, 256, 0, stream>>>(pval, pidx, qsq, idx, hist, acc);
  k_gather<<<dim3(1024, B_), 256, 0, stream>>>(x, embT, idx, out);
  k_perp<<<B_, 256, 0, stream>>>(hist, acc, out);
}

// Round 4
// 217.990 us; speedup vs baseline: 1.0724x; 1.0002x over previous
//
#include <hip/hip_runtime.h>
#include <hip/hip_bf16.h>
#include <stdint.h>

#define B_   8
#define S_   4096
#define SP1_ 4097
#define D_   256
#define R_   512
#define C_   2048
#define BS_  32768          // B*S

typedef __attribute__((ext_vector_type(8))) short bf16x8;
typedef __attribute__((ext_vector_type(4))) float f32x4;
typedef unsigned short u16;

__device__ __forceinline__ u16 f2bf(float f) {
  __hip_bfloat16 h = __float2bfloat16(f);
  return *(u16*)&h;
}
__device__ __forceinline__ float bf2f(u16 u) {
  __hip_bfloat16 h = *(__hip_bfloat16*)&u;
  return __bfloat162float(h);
}

// async global->LDS, 16B per lane; LDS dst = wave-uniform base + lane*16
__device__ __forceinline__ void gload16(const u16* g, u16* l) {
  __builtin_amdgcn_global_load_lds(
      (const __attribute__((address_space(1))) uint32_t*)g,
      (__attribute__((address_space(3))) uint32_t*)l, 16, 0, 0);
}

// ================= K1: prep (cast+qsq | w0 | transpose_E | zero | cls copy) =================
#define NCAST 8192
#define W0B   (NCAST)            // 64 blocks
#define TEB   (W0B + 64)         // 1024 blocks
#define ZB    (TEB + 1024)       // 33 blocks
#define CLSB  (ZB + 33)          // 8 blocks
#define K1GRID (CLSB + 8)

__global__ void k_prep(const float* __restrict__ x, const float* __restrict__ clsw,
                       const float* __restrict__ E, u16* __restrict__ posb,
                       float* __restrict__ qsq, float* __restrict__ w0,
                       u16* __restrict__ ET, float* __restrict__ zbase,
                       float* __restrict__ out) {
  __shared__ float sm[33 * 32];
  int blk = blockIdx.x, t = threadIdx.x;
  if (blk < NCAST) {
    // cast pos tokens + per-row q_sq: 4 rows/block, one per wave
    int wv = t >> 6, lane = t & 63;
    int row = blk * 4 + wv;
    int b = row >> 12, s = row & 4095;
    const float4 v = *(const float4*)(x + (size_t)b * SP1_ * D_ + (size_t)(s + 1) * D_ + lane * 4);
    ushort4 u;
    u.x = f2bf(v.x); u.y = f2bf(v.y); u.z = f2bf(v.z); u.w = f2bf(v.w);
    *(ushort4*)(posb + (size_t)row * D_ + lane * 4) = u;
    float ss = v.x * v.x + v.y * v.y + v.z * v.z + v.w * v.w;
    #pragma unroll
    for (int off = 1; off < 64; off <<= 1) ss += __shfl_xor(ss, off);
    if (lane == 0) qsq[row] = ss;
  } else if (blk < TEB) {
    // w0[b,r] = sum_d cls[b,d]*clsw[d,r]
    int id = blk - W0B;                       // 0..63 = b*8 + rc
    int b = id >> 3, rc = id & 7;
    int r = rc * 64 + (t & 63);
    int dg = t >> 6;
    const float* cls = x + (size_t)b * SP1_ * D_;
    float a = 0.f;
    for (int d = dg * 64; d < dg * 64 + 64; d++) a += cls[d] * clsw[d * R_ + r];
    sm[t] = a;
    __syncthreads();
    if (t < 64) w0[b * R_ + r] = sm[t] + sm[t + 64] + sm[t + 128] + sm[t + 192];
  } else if (blk < ZB) {
    // ET[c,r] = bf16(E[r,c])
    int id = blk - TEB;                       // 0..1023
    int c0 = (id & 63) * 32, r0 = (id >> 6) * 32;
    int tx = t & 31, ty = t >> 5;             // 32 x 8
    float (*tile)[33] = (float(*)[33])sm;
    #pragma unroll
    for (int i = 0; i < 4; i++)
      tile[ty + i * 8][tx] = E[(size_t)(r0 + ty + i * 8) * C_ + c0 + tx];
    __syncthreads();
    #pragma unroll
    for (int i = 0; i < 4; i++)
      ET[(size_t)(c0 + ty + i * 8) * R_ + r0 + tx] = f2bf(tile[tx][ty + i * 8]);
  } else if (blk < CLSB) {
    // zero esq/hist/acc region: 131328 B = 32832 u32
    int id = blk - ZB;
    int o = id * 1024 + t;
    if (o < 32832) ((uint32_t*)zbase)[o] = 0u;
    o += 256;  // cover 1024 u32 per block with 256 threads x4
    if (t < 256) {
      int o2 = id * 1024 + 256 + t; if (o2 < 32832) ((uint32_t*)zbase)[o2] = 0u;
      int o3 = id * 1024 + 512 + t; if (o3 < 32832) ((uint32_t*)zbase)[o3] = 0u;
      int o4 = id * 1024 + 768 + t; if (o4 < 32832) ((uint32_t*)zbase)[o4] = 0u;
    }
  } else {
    // cls token passthrough: 1 block per b
    int b = blk - CLSB;
    size_t xb = (size_t)b * SP1_ * D_;
    if (t < 64) *(float4*)(out + xb + t * 4) = *(const float4*)(x + xb + t * 4);
  }
}

// ================= K2: softmax -> proj bf16 =================
__global__ void k_softmax(const float* __restrict__ x, const float* __restrict__ w0,
                          const float* __restrict__ clsb, u16* __restrict__ proj) {
  int bd = blockIdx.x;
  int b = bd >> 8, d = bd & 255;
  float c = x[(size_t)b * SP1_ * D_ + d];
  int t = threadIdx.x;
  float l0 = c * w0[b * R_ + t] + clsb[t];
  float l1 = c * w0[b * R_ + t + 256] + clsb[t + 256];
  __shared__ float red[256];
  red[t] = fmaxf(l0, l1);
  __syncthreads();
  for (int st = 128; st; st >>= 1) { if (t < st) red[t] = fmaxf(red[t], red[t + st]); __syncthreads(); }
  float m = red[0];
  __syncthreads();
  float e0 = expf(l0 - m), e1 = expf(l1 - m);
  red[t] = e0 + e1;
  __syncthreads();
  for (int st = 128; st; st >>= 1) { if (t < st) red[t] += red[t + st]; __syncthreads(); }
  float inv = 1.0f / red[0];
  size_t base = ((size_t)b * D_ + d) * R_;
  proj[base + t]       = f2bf(e0 * inv);
  proj[base + t + 256] = f2bf(e1 * inv);
}

// ================= K3: emb GEMM (64x128): embT[b,c,d], esq =================
__global__ __launch_bounds__(256) void k_gemm_emb(const u16* __restrict__ proj,
                                                  const u16* __restrict__ ET,
                                                  u16* __restrict__ embT,
                                                  float* __restrict__ esq) {
  int ct = blockIdx.x, mt = blockIdx.y, b = blockIdx.z;
  int n0 = ct * 128, m0 = mt * 64;
  const u16* A  = proj + (size_t)b * D_ * R_;
  const u16* Bt = ET;
  __shared__ u16 tA[2048], tB[4096];
  int tid = threadIdx.x;
  int wv = tid >> 6, lane = tid & 63, ln = lane & 15, qd = lane >> 4;
  int srow = lane >> 2;
  int scol = (((lane & 3) ^ (srow & 3) ^ ((srow >> 2) & 3))) * 8;
  const u16* gA0 = A  + (size_t)(m0 + wv * 16 + srow) * R_ + scol;
  const u16* gB0 = Bt + (size_t)(n0 + wv * 16 + srow) * R_ + scol;
  const u16* gB1 = gB0 + (size_t)64 * R_;
  u16* lA0 = &tA[(wv * 16) * 32];
  u16* lB0 = &tB[(wv * 16) * 32];
  u16* lB1 = &tB[(64 + wv * 16) * 32];
  int cs8 = ((qd ^ (ln & 3) ^ ((ln >> 2) & 3))) * 8;
  f32x4 acc[8];
  #pragma unroll
  for (int nf = 0; nf < 8; nf++) acc[nf] = (f32x4){0.f, 0.f, 0.f, 0.f};

  for (int kk = 0; kk < R_; kk += 32) {
    __syncthreads();
    gload16(gA0 + kk, lA0);
    gload16(gB0 + kk, lB0);
    gload16(gB1 + kk, lB1);
    __syncthreads();
    bf16x8 af = *(bf16x8*)&tA[(wv * 16 + ln) * 32 + cs8];
    bf16x8 bfr[8];
    #pragma unroll
    for (int nf = 0; nf < 8; nf++) bfr[nf] = *(bf16x8*)&tB[(nf * 16 + ln) * 32 + cs8];
    #pragma unroll
    for (int nf = 0; nf < 8; nf++)
      acc[nf] = __builtin_amdgcn_mfma_f32_16x16x32_bf16(af, bfr[nf], acc[nf], 0, 0, 0);
  }
  #pragma unroll
  for (int nf = 0; nf < 8; nf++) {
    int c = n0 + nf * 16 + ln;
    int dbase = m0 + wv * 16 + qd * 4;
    f32x4 v = acc[nf];
    ushort4 u;
    u.x = f2bf(v[0]); u.y = f2bf(v[1]); u.z = f2bf(v[2]); u.w = f2bf(v[3]);
    *(ushort4*)&embT[((size_t)b * C_ + c) * D_ + dbase] = u;
    float ss = v[0]*v[0] + v[1]*v[1] + v[2]*v[2] + v[3]*v[3];
    ss += __shfl_xor(ss, 16);
    ss += __shfl_xor(ss, 32);
    if (qd == 0) atomicAdd(&esq[b * C_ + c], ss);
  }
}

// ================= K4: dist GEMM 128x128, BK=64, 2x2 waves, packed partial writes =================
// LDS tiles: 128 rows x 64 u16 (128B rows, 8 x 16B chunk-slots). Swizzle: slot = chunk ^ (row&7).
__global__ __launch_bounds__(256) void k_gemm_dist(const u16* __restrict__ posb,
                                                   const u16* __restrict__ embT,
                                                   const float* __restrict__ esq,
                                                   float* __restrict__ pval,
                                                   int* __restrict__ pidx) {
  int ct = blockIdx.x, st = blockIdx.y, b = blockIdx.z;
  int n0 = ct * 128, m0 = st * 128;
  const u16* A  = posb + (size_t)b * S_ * D_;   // S x D
  const u16* Bt = embT + (size_t)b * C_ * D_;   // C x D
  __shared__ u16 tA[8192], tB[8192];            // 128 x 64 each (16KB)
  __shared__ float sh_esq[128];
  __shared__ float pbv[256];
  __shared__ int   pbi[256];
  int tid = threadIdx.x;
  if (tid < 128) sh_esq[tid] = esq[b * C_ + n0 + tid];
  int wv = tid >> 6, lane = tid & 63, ln = lane & 15, qd = lane >> 4;
  int wr = wv >> 1, wc = wv & 1;                // 2x2 wave grid
  // staging: wave covers 32 rows (4 calls x 8 rows); lane: srow8 = lane>>3, sc = lane&7
  int srow8 = lane >> 3, sc = lane & 7;
  int gc = sc ^ srow8;                          // global 16B-chunk to fetch so it lands at slot sc
  f32x4 acc[4][4];
  #pragma unroll
  for (int mi = 0; mi < 4; mi++)
    #pragma unroll
    for (int ni = 0; ni < 4; ni++) acc[mi][ni] = (f32x4){0.f, 0.f, 0.f, 0.f};

  for (int kk = 0; kk < D_; kk += 64) {
    __syncthreads();
    #pragma unroll
    for (int i = 0; i < 4; i++) {
      int r = wv * 32 + i * 8 + srow8;
      gload16(A  + (size_t)(m0 + r) * D_ + kk + gc * 8, &tA[(wv * 32 + i * 8) * 64]);
      gload16(Bt + (size_t)(n0 + r) * D_ + kk + gc * 8, &tB[(wv * 32 + i * 8) * 64]);
    }
    __syncthreads();
    #pragma unroll
    for (int kc = 0; kc < 2; kc++) {
      bf16x8 af[4], bf[4];
      #pragma unroll
      for (int mi = 0; mi < 4; mi++) {
        int row = wr * 64 + mi * 16 + ln;
        int slot = (kc * 4 + qd) ^ (ln & 7);
        af[mi] = *(bf16x8*)&tA[row * 64 + slot * 8];
      }
      #pragma unroll
      for (int ni = 0; ni < 4; ni++) {
        int row = wc * 64 + ni * 16 + ln;
        int slot = (kc * 4 + qd) ^ (ln & 7);
        bf[ni] = *(bf16x8*)&tB[row * 64 + slot * 8];
      }
      #pragma unroll
      for (int mi = 0; mi < 4; mi++)
        #pragma unroll
        for (int ni = 0; ni < 4; ni++)
          acc[mi][ni] = __builtin_amdgcn_mfma_f32_16x16x32_bf16(af[mi], bf[ni], acc[mi][ni], 0, 0, 0);
    }
  }
  // per-row argmin over this wave's 64 cols; rows local rl = mi*16 + qd*4 + reg
  #pragma unroll
  for (int mi = 0; mi < 4; mi++) {
    #pragma unroll
    for (int reg = 0; reg < 4; reg++) {
      float bv = 3.4e38f; int bc = 0;
      #pragma unroll
      for (int ni = 0; ni < 4; ni++) {
        int c = wc * 64 + ni * 16 + ln;       // local col in [0,128)
        float sc2 = sh_esq[c] - 2.0f * acc[mi][ni][reg];
        if (sc2 < bv || (sc2 == bv && c < bc)) { bv = sc2; bc = c; }
      }
      #pragma unroll
      for (int off = 1; off < 16; off <<= 1) {
        float ov = __shfl_xor(bv, off);
        int   oc = __shfl_xor(bc, off);
        if (ov < bv || (ov == bv && oc < bc)) { bv = ov; bc = oc; }
      }
      if (ln == 0) {
        int rl = mi * 16 + qd * 4 + reg;      // row local to wave's 64 rows
        int slot = (wr * 2 + wc) * 64 + rl;
        pbv[slot] = bv;
        pbi[slot] = bc;
      }
    }
  }
  __syncthreads();
  // combine wc halves, write coalesced: pval layout [ct][b*S+s]
  if (tid < 128) {
    int wrr = tid >> 6, rl = tid & 63;
    float v0 = pbv[(wrr * 2 + 0) * 64 + rl]; int i0 = pbi[(wrr * 2 + 0) * 64 + rl];
    float v1 = pbv[(wrr * 2 + 1) * 64 + rl]; int i1 = pbi[(wrr * 2 + 1) * 64 + rl];
    if (v1 < v0 || (v1 == v0 && i1 < i0)) { v0 = v1; i0 = i1; }
    size_t o = (size_t)ct * BS_ + b * S_ + m0 + tid;
    pval[o] = v0;
    pidx[o] = n0 + i0;
  }
}

// ================= K5: reduce partials + hist + SSE + gather + write out =================
__global__ void k_reduce_gather(const float* __restrict__ pval, const int* __restrict__ pidx,
                                const float* __restrict__ qsq, const u16* __restrict__ embT,
                                int* __restrict__ hist, float* __restrict__ acc,
                                float* __restrict__ out) {
  int blk = blockIdx.x;                       // 512 blocks x 64 rows
  int t = threadIdx.x;
  int wv = t >> 6, lane = t & 63;
  int g0 = blk * 64;                          // first global row (b*S+s)
  int b = g0 >> 12;
  __shared__ float vbuf[4][64];
  __shared__ int   ibuf[4][64];
  __shared__ int   fidx[64];
  int g = g0 + lane;
  float bv = 3.4e38f; int bi = 0;
  #pragma unroll
  for (int j = 0; j < 4; j++) {
    int ctn = wv * 4 + j;
    float v = pval[(size_t)ctn * BS_ + g];
    int  ix = pidx[(size_t)ctn * BS_ + g];
    if (v < bv || (v == bv && ix < bi)) { bv = v; bi = ix; }
  }
  vbuf[wv][lane] = bv;
  ibuf[wv][lane] = bi;
  __syncthreads();
  if (t < 64) {
    float fv = vbuf[0][t]; int fi = ibuf[0][t];
    #pragma unroll
    for (int w = 1; w < 4; w++) {
      float v = vbuf[w][t]; int ix = ibuf[w][t];
      if (v < fv || (v == fv && ix < fi)) { fv = v; fi = ix; }
    }
    fidx[t] = fi;
    atomicAdd(&hist[b * C_ + fi], 1);
    float sse = fv + qsq[g0 + t];
    #pragma unroll
    for (int off = 1; off < 64; off <<= 1) sse += __shfl_xor(sse, off);
    if (t == 0) atomicAdd(&acc[0], sse);
  }
  __syncthreads();
  // gather: wave wv writes rows [wv*16, wv*16+16)
  size_t xb = (size_t)b * SP1_ * D_;
  const u16* eb = embT + (size_t)b * C_ * D_;
  #pragma unroll
  for (int j = 0; j < 16; j++) {
    int r = wv * 16 + j;
    int ix = fidx[r];
    int s = (g0 + r) & 4095;
    ushort4 q4 = *(const ushort4*)(eb + (size_t)ix * D_ + lane * 4);
    float4 q;
    q.x = bf2f(q4.x); q.y = bf2f(q4.y); q.z = bf2f(q4.z); q.w = bf2f(q4.w);
    *(float4*)(out + xb + (size_t)(s + 1) * D_ + lane * 4) = q;
  }
}

// ================= K6: perplexity + final scalars =================
__global__ void k_perp(const int* __restrict__ hist, float* __restrict__ acc,
                       float* __restrict__ out) {
  int b = blockIdx.x, t = threadIdx.x;
  float ps = 0.f;
  for (int c = t; c < C_; c += 256) {
    float p = (float)hist[b * C_ + c] * (1.0f / (float)S_);
    ps += p * logf(p + 1e-10f);
  }
  __shared__ float red[256];
  red[t] = ps;
  __syncthreads();
  for (int st = 128; st; st >>= 1) { if (t < st) red[t] += red[t + st]; __syncthreads(); }
  if (t == 0) {
    atomicAdd(&acc[1], expf(-red[0]) * (1.0f / (float)B_));
    __threadfence();
    int done = atomicAdd((int*)acc + 2, 1);
    if (done == B_ - 1) {
      float P = atomicAdd(&acc[1], 0.0f);
      float SSE = atomicAdd(&acc[0], 0.0f);
      float L = SSE * (1.0f / 8388608.0f);
      size_t base = (size_t)B_ * SP1_ * D_;
      out[base + 0] = P;
      out[base + 1] = L;
      out[base + 2] = L;
      out[base + 3] = L + 0.25f * L;
    }
  }
}

// ---------------- workspace layout (bytes); esq/hist/acc contiguous (zeroed by K1) ----------------
#define OFF_W0    0u
#define OFF_ESQ   16384u
#define OFF_HIST  (OFF_ESQ + 65536u)
#define OFF_ACC   (OFF_HIST + 65536u)
#define OFF_PROJ  (OFF_ACC + 256u)
#define OFF_ET    (OFF_PROJ + 2097152u)
#define OFF_EMBT  (OFF_ET + 2097152u)
#define OFF_POSB  (OFF_EMBT + 8388608u)
#define OFF_PVAL  (OFF_POSB + 16777216u)
#define OFF_PIDX  (OFF_PVAL + 2097152u)
#define OFF_QSQ   (OFF_PIDX + 2097152u)

extern "C" void kernel_launch(void* const* d_in, const int* in_sizes, int n_in,
                              void* d_out, int out_size, void* d_ws, size_t ws_size,
                              hipStream_t stream) {
  (void)in_sizes; (void)n_in; (void)out_size; (void)ws_size;
  const float* x    = (const float*)d_in[0];
  const float* E    = (const float*)d_in[1];
  const float* clsw = (const float*)d_in[2];
  const float* clsb = (const float*)d_in[3];
  float* out = (float*)d_out;

  char* ws = (char*)d_ws;
  float* w0   = (float*)(ws + OFF_W0);
  float* esq  = (float*)(ws + OFF_ESQ);
  int*   hist = (int*)  (ws + OFF_HIST);
  float* acc  = (float*)(ws + OFF_ACC);
  u16*   proj = (u16*)  (ws + OFF_PROJ);
  u16*   ET   = (u16*)  (ws + OFF_ET);
  u16*   embT = (u16*)  (ws + OFF_EMBT);
  u16*   posb = (u16*)  (ws + OFF_POSB);
  float* pval = (float*)(ws + OFF_PVAL);
  int*   pidx = (int*)  (ws + OFF_PIDX);
  float* qsq  = (float*)(ws + OFF_QSQ);

  k_prep<<<K1GRID, 256, 0, stream>>>(x, clsw, E, posb, qsq, w0, ET, esq, out);
  k_softmax<<<B_ * D_, 256, 0, stream>>>(x, w0, clsb, proj);
  k_gemm_emb<<<dim3(16, 4, B_), 256, 0, stream>>>(proj, ET, embT, esq);
  k_gemm_dist<<<dim3(16, 32, B_), 256, 0, stream>>>(posb, embT, esq, pval, pidx);
  k_reduce_gather<<<512, 256, 0, stream>>>(pval, pidx, qsq, embT, hist, acc, out);
  k_perp<<<B_, 256, 0, stream>>>(hist, acc, out);
}